// Round 5
// baseline (153.668 us; speedup 1.0000x reference)
//
#include <hip/hip_runtime.h>
#include <hip/hip_bf16.h>
#include <stdint.h>

#define BB 2
#define SS 4096
#define EE 640
#define HH 4
#define DD 256
#define WIN 512

typedef __attribute__((ext_vector_type(8))) short bv8;   // 8 bf16 (4 VGPR)
typedef __attribute__((ext_vector_type(4))) float fv4;

__device__ __forceinline__ unsigned short f2b(float f) {
  union { float f; unsigned u; } a; a.f = f;
  unsigned r = a.u + 0x7fffu + ((a.u >> 16) & 1u);   // RNE
  return (unsigned short)(r >> 16);
}
__device__ __forceinline__ float b2f(unsigned short s) {
  union { unsigned u; float f; } a; a.u = ((unsigned)s) << 16;
  return a.f;
}

typedef const __attribute__((address_space(1))) unsigned int* as1u;
typedef __attribute__((address_space(3))) unsigned int* as3u;
__device__ __forceinline__ void gld16(const unsigned short* g, unsigned short* l) {
  // async global->LDS, 16B/lane; LDS dst = wave-uniform base + lane*16
  __builtin_amdgcn_global_load_lds((as1u)(const void*)g, (as3u)(void*)l, 16, 0, 0);
}

// ---------------- f32 -> bf16 cast (x) ----------------
__global__ __launch_bounds__(256) void k_cast_bf16(const float* __restrict__ src,
                                                   unsigned short* __restrict__ dst, int n4) {
  int i = blockIdx.x * 256 + threadIdx.x;
  if (i >= n4) return;
  fv4 v = ((const fv4*)src)[i];
  ushort4 o; o.x = f2b(v.x); o.y = f2b(v.y); o.z = f2b(v.z); o.w = f2b(v.w);
  ((ushort4*)dst)[i] = o;
}

// ---------------- tiled transpose + cast to bf16 ----------------
template <typename T>
__global__ __launch_bounds__(256) void k_transpose_bf16(const T* __restrict__ src,
    unsigned short* __restrict__ dst, int sstride, int dstride) {
  __shared__ float tile[32][33];
  int r0 = blockIdx.x * 32, c0 = blockIdx.y * 32;
  int t = threadIdx.x;
  int rr = t >> 3, cc = (t & 7) * 4;
  const T* p = src + (size_t)(r0 + rr) * sstride + c0 + cc;
  float v[4];
  if constexpr (sizeof(T) == 4) {
    fv4 x = *(const fv4*)p;
    v[0] = x.x; v[1] = x.y; v[2] = x.z; v[3] = x.w;
  } else {
    ushort4 x = *(const ushort4*)p;
    v[0] = b2f(x.x); v[1] = b2f(x.y); v[2] = b2f(x.z); v[3] = b2f(x.w);
  }
#pragma unroll
  for (int i = 0; i < 4; ++i) tile[cc + i][rr] = v[i];
  __syncthreads();
  ushort4 o;
  o.x = f2b(tile[rr][cc + 0]); o.y = f2b(tile[rr][cc + 1]);
  o.z = f2b(tile[rr][cc + 2]); o.w = f2b(tile[rr][cc + 3]);
  *(ushort4*)(dst + (size_t)(c0 + rr) * dstride + r0 + cc) = o;
}

// ---------------- bf16 GEMM (m97 structure): C(MxN) = A(MxK) * Bt(NxK)^T ----
template <bool OUT_BF16, int BN>
__global__ __launch_bounds__(256) void k_gemm(const unsigned short* __restrict__ A,
    const unsigned short* __restrict__ Bt, void* __restrict__ Cp,
    int M, int N, int K, int nt_n) {
  __shared__ unsigned short la[128 * 32];
  __shared__ unsigned short lb[BN * 32];
  const int bid = blockIdx.x;
  const int gidx = (bid & 7) * (gridDim.x >> 3) + (bid >> 3);
  const int m0 = (gidx / nt_n) * 128, n0 = (gidx % nt_n) * BN;
  const int tid = threadIdx.x, lane = tid & 63, wave = tid >> 6;
  const int g = lane >> 4, lr = lane & 15;
  constexpr int MI = (BN == 128) ? 4 : 2;
  const int wm = (BN == 128) ? (wave >> 1) * 64 : wave * 32;
  const int wn = (BN == 128) ? (wave & 1) * 64 : 0;
  fv4 acc[MI][4] = {};
  const int srow = wave * 32 + (lane >> 2);
  const int sch = (lane & 3) * 8;
  const unsigned short* ga0 = A + (size_t)(m0 + srow) * K + sch;
  unsigned short* lad = la + wave * 1024;
  const int srowb = (BN == 128) ? srow : (wave * 16 + (lane >> 2));
  const unsigned short* gb0 = Bt + (size_t)(n0 + srowb) * K + sch;
  unsigned short* lbd = lb + ((BN == 128) ? wave * 1024 : wave * 512);
  for (int k0 = 0; k0 < K; k0 += 32) {
    __syncthreads();
    gld16(ga0 + k0, lad);
    gld16(ga0 + (size_t)16 * K + k0, lad + 512);
    gld16(gb0 + k0, lbd);
    if constexpr (BN == 128) gld16(gb0 + (size_t)16 * K + k0, lbd + 512);
    __syncthreads();
    bv8 af[MI], bf[4];
#pragma unroll
    for (int mi = 0; mi < MI; ++mi) af[mi] = *(const bv8*)(la + (wm + mi * 16 + lr) * 32 + g * 8);
#pragma unroll
    for (int ni = 0; ni < 4; ++ni) bf[ni] = *(const bv8*)(lb + (wn + ni * 16 + lr) * 32 + g * 8);
    __builtin_amdgcn_s_setprio(1);
#pragma unroll
    for (int mi = 0; mi < MI; ++mi)
#pragma unroll
      for (int ni = 0; ni < 4; ++ni)
        acc[mi][ni] = __builtin_amdgcn_mfma_f32_16x16x32_bf16(af[mi], bf[ni], acc[mi][ni], 0, 0, 0);
    __builtin_amdgcn_s_setprio(0);
  }
#pragma unroll
  for (int mi = 0; mi < MI; ++mi) {
#pragma unroll
    for (int r = 0; r < 4; ++r) {
      size_t row = (size_t)(m0 + wm + mi * 16 + g * 4 + r);
#pragma unroll
      for (int ni = 0; ni < 4; ++ni) {
        int col = n0 + wn + ni * 16 + lr;
        float val = acc[mi][ni][r];
        if constexpr (OUT_BF16)
          ((unsigned short*)Cp)[row * N + col] = f2b(val);
        else
          ((float*)Cp)[row * N + col] = val;
      }
    }
  }
}

// ---------------- rmsnorm + rope (+ SCALING folded into q), bf16 out --------
// one block per (b,s) row; waves 0-3: q heads, wave 4: k  (qkv stride 1536)
__global__ __launch_bounds__(320) void k_normrope(const unsigned short* __restrict__ qkv,
    const float* __restrict__ cosp, const float* __restrict__ sinp,
    const float* __restrict__ qsc, const float* __restrict__ ksc,
    unsigned short* __restrict__ qo, unsigned short* __restrict__ ko) {
  int m = blockIdx.x;
  int b = m >> 12, s = m & 4095;
  int wave = threadIdx.x >> 6, lane = threadIdx.x & 63;
  bool isq = wave < 4;
  const unsigned short* src = qkv + (size_t)m * 1536 + (isq ? wave * 256 : 1024);
  const float* scp = isq ? qsc : ksc;
  int d0 = lane * 4;
  ushort4 raw = *(const ushort4*)(src + d0);
  float x0 = b2f(raw.x), x1 = b2f(raw.y), x2 = b2f(raw.z), x3 = b2f(raw.w);
  float ss = x0 * x0 + x1 * x1 + x2 * x2 + x3 * x3;
#pragma unroll
  for (int off = 1; off < 64; off <<= 1) ss += __shfl_xor(ss, off, 64);
  float rs = rsqrtf(ss * (1.0f / 256.0f) + 1e-6f);
  fv4 sc = *(const fv4*)(scp + d0);
  float n0 = x0 * rs * (1.0f + sc.x);
  float n1 = x1 * rs * (1.0f + sc.y);
  float n2 = x2 * rs * (1.0f + sc.z);
  float n3 = x3 * rs * (1.0f + sc.w);
  float p0 = __shfl_xor(n0, 32, 64);
  float p1 = __shfl_xor(n1, 32, 64);
  float p2 = __shfl_xor(n2, 32, 64);
  float p3 = __shfl_xor(n3, 32, 64);
  float sgn = (lane < 32) ? -1.0f : 1.0f;
  fv4 c4 = *(const fv4*)(cosp + (size_t)s * 256 + d0);
  fv4 s4 = *(const fv4*)(sinp + (size_t)s * 256 + d0);
  float mult = isq ? 0.0625f : 1.0f;
  float o0 = (n0 * c4.x + sgn * p0 * s4.x) * mult;
  float o1 = (n1 * c4.y + sgn * p1 * s4.y) * mult;
  float o2 = (n2 * c4.z + sgn * p2 * s4.z) * mult;
  float o3 = (n3 * c4.w + sgn * p3 * s4.w) * mult;
  ushort4 o; o.x = f2b(o0); o.y = f2b(o1); o.z = f2b(o2); o.w = f2b(o3);
  unsigned short* dst = isq
      ? qo + ((size_t)(b * HH + wave) * SS + s) * 256 + d0
      : ko + ((size_t)b * SS + s) * 256 + d0;
  *(ushort4*)dst = o;
}

// ---------------- flash attention, sliding window 512 ----------------------
// 8-wave block (512 thr), 128 q-rows. Wave-groups split the KEY range:
// waves 0-3 first half of tiles, waves 4-7 second half (fixed-max softmax
// makes partials linear; combined once at the end via LDS). Each wave owns
// 32 q-rows (Mrep=2). K-tile 32 keys; per-group double-buffered K+V staged
// with global_load_lds + both-sides XOR swizzle. 1 barrier per tile.
// Scores bounded by 16 (RMSNorm norms=16, RoPE norm-preserving, SCALING=1/16).
__global__ __launch_bounds__(512, 2) void k_attn(const unsigned short* __restrict__ q,
    const unsigned short* __restrict__ kg, const unsigned short* __restrict__ vtg,
    unsigned short* __restrict__ att) {
  __shared__ unsigned short ldsKV[65536];   // 128 KB: [grp][{K:2x8192, V:2x8192}]
  __shared__ unsigned short pl[8][32 * 40]; // 20 KB per-wave P [qrow32][key32 pad40]
  const int plane = blockIdx.x & 7;         // XCD id == (h,b) plane
  const int h = plane & 3, b = plane >> 2;
  const int i0 = (blockIdx.x >> 3) * 128;
  const int tid = threadIdx.x, wave = tid >> 6, lane = tid & 63;
  const int grp = wave >> 2, gw = wave & 3;
  const int g = lane >> 4, lr = lane & 15;
  unsigned short* ktg = ldsKV + grp * 32768;            // [2][32*256]
  unsigned short* vlg = ldsKV + grp * 32768 + 16384;    // [2][8192] swizzled V^T
  // Q fragments: 32 rows per wave (same rows in both groups)
  bv8 qf[2][8];
#pragma unroll
  for (int mi = 0; mi < 2; ++mi) {
    const unsigned short* qp =
        q + ((size_t)(b * HH + h) * SS + i0 + gw * 32 + mi * 16 + lr) * 256;
#pragma unroll
    for (int kk = 0; kk < 8; ++kk) qf[mi][kk] = *(const bv8*)(qp + kk * 32 + g * 8);
  }
  fv4 po[2][16] = {};
  float lsp[2][4] = {};
  const int t0 = (i0 >= WIN) ? ((i0 - WIN + 1) >> 5) : 0;
  const int t1 = (i0 >> 5) + 3;
  const int cnt = t1 - t0 + 1;
  const int h0 = (cnt + 1) >> 1;        // group0 tile count == NITER
  const int g1n = cnt - h0;             // group1 tile count (<= h0)
  const unsigned short* kb = kg + (size_t)b * SS * 256;
  const unsigned short* vb = vtg + (size_t)b * 256 * SS;  // vt is (B,D,S)
  // K stage: 32 rows x 512B; LDS slot s of row r holds global chunk s^(r&7)
  auto stageK = [&](int t, int p) {
    const unsigned short* kbase = kb + (size_t)t * 32 * 256;
#pragma unroll
    for (int c = 0; c < 4; ++c) {
      int row_ = gw * 8 + c * 2 + (lane >> 5);
      int sch_ = ((lane & 31) ^ (row_ & 7)) * 8;
      gld16(kbase + (size_t)row_ * 256 + sch_, ktg + p * 8192 + (gw * 8 + c * 2) * 256);
    }
  };
  // V stage: 256 d-rows x 64B; 128B super-rows of 8 slots, slot s of super-row
  // sr holds global (d = 2sr + bit2(s^(sr&7)), chunk = (s^(sr&7))&3)
  auto stageV = [&](int t, int p) {
#pragma unroll
    for (int c = 0; c < 4; ++c) {
      int qid = gw * 64 + c * 256 + lane;      // 16B slot id 0..1023
      int sr = qid >> 3, s = qid & 7;
      int e = s ^ (sr & 7);
      int d_ = 2 * sr + ((e >> 2) & 1);
      int ch = e & 3;
      gld16(vb + (size_t)d_ * SS + (size_t)t * 32 + ch * 8,
            vlg + p * 8192 + (gw * 64 + c * 256) * 8);
    }
  };
  {
    int tI = t0 + (grp ? h0 : 0);
    bool v0 = grp ? (0 < g1n) : true;
    int tc = v0 ? tI : t0;
    stageK(tc, 0); stageV(tc, 0);
  }
  for (int i = 0; i < h0; ++i) {
    const int p = i & 1;
    __syncthreads();   // drains staging of buf p; prior iter's reads of p^1 done
    if (i + 1 < h0) {
      int tn = t0 + (grp ? h0 : 0) + i + 1;
      bool vn = grp ? (i + 1 < g1n) : true;
      int tc = vn ? tn : t0;
      stageK(tc, p ^ 1); stageV(tc, p ^ 1);
    }
    const int tc = t0 + (grp ? h0 : 0) + i;
    const bool vg = grp ? (i < g1n) : true;
    fv4 sa[2][2] = {};
    __builtin_amdgcn_s_setprio(1);
#pragma unroll
    for (int n2 = 0; n2 < 2; ++n2) {
      const int row_ = n2 * 16 + lr;
#pragma unroll
      for (int kk = 0; kk < 8; ++kk) {
        bv8 kf = *(const bv8*)(ktg + p * 8192 + row_ * 256 + (((kk * 4 + g) ^ (row_ & 7)) * 8));
        sa[0][n2] = __builtin_amdgcn_mfma_f32_16x16x32_bf16(qf[0][kk], kf, sa[0][n2], 0, 0, 0);
        sa[1][n2] = __builtin_amdgcn_mfma_f32_16x16x32_bf16(qf[1][kk], kf, sa[1][n2], 0, 0, 0);
      }
    }
    __builtin_amdgcn_s_setprio(0);
    const int jb = tc * 32;
    const bool nm = !vg || (jb + 31 > i0) || (i0 + 127 - jb >= WIN);
    if (nm) {
#pragma unroll
      for (int mi = 0; mi < 2; ++mi)
#pragma unroll
        for (int n2 = 0; n2 < 2; ++n2) {
          int j = jb + n2 * 16 + lr;
#pragma unroll
          for (int r = 0; r < 4; ++r) {
            int row = i0 + gw * 32 + mi * 16 + g * 4 + r;
            if (!vg || j > row || row - j >= WIN) sa[mi][n2][r] = -1e30f;
          }
        }
    }
#pragma unroll
    for (int mi = 0; mi < 2; ++mi)
#pragma unroll
      for (int n2 = 0; n2 < 2; ++n2)
#pragma unroll
        for (int r = 0; r < 4; ++r) {
          float pe = __expf(sa[mi][n2][r] - 16.5f);
          lsp[mi][r] += pe;
          pl[wave][(mi * 16 + g * 4 + r) * 40 + n2 * 16 + lr] = f2b(pe);
        }
    bv8 pf0 = *(const bv8*)(&pl[wave][lr * 40 + g * 8]);
    bv8 pf1 = *(const bv8*)(&pl[wave][(16 + lr) * 40 + g * 8]);
    __builtin_amdgcn_s_setprio(1);
#pragma unroll
    for (int n = 0; n < 16; ++n) {
      const int d_ = n * 16 + lr;
      const int sr = d_ >> 1;
      const int s_ = (g + 4 * (d_ & 1)) ^ (sr & 7);
      bv8 vf = *(const bv8*)(vlg + p * 8192 + sr * 64 + s_ * 8);
      po[0][n] = __builtin_amdgcn_mfma_f32_16x16x32_bf16(pf0, vf, po[0][n], 0, 0, 0);
      po[1][n] = __builtin_amdgcn_mfma_f32_16x16x32_bf16(pf1, vf, po[1][n], 0, 0, 0);
    }
    __builtin_amdgcn_s_setprio(0);
  }
  // ---- combine the two key-range halves (partials are linear) ----
  __syncthreads();
  float* posh = (float*)ldsKV;          // 128 x 256 f32 = 128 KB
  float* lsh = (float*)pl;              // 4*64*8 f32 = 8 KB
  if (grp == 1) {
#pragma unroll
    for (int mi = 0; mi < 2; ++mi)
#pragma unroll
      for (int n = 0; n < 16; ++n)
#pragma unroll
        for (int r = 0; r < 4; ++r)
          posh[(gw * 32 + mi * 16 + g * 4 + r) * 256 + n * 16 + lr] = po[mi][n][r];
#pragma unroll
    for (int mi = 0; mi < 2; ++mi)
#pragma unroll
      for (int r = 0; r < 4; ++r) lsh[(gw * 64 + lane) * 8 + mi * 4 + r] = lsp[mi][r];
  }
  __syncthreads();
  if (grp == 0) {
#pragma unroll
    for (int mi = 0; mi < 2; ++mi)
#pragma unroll
      for (int n = 0; n < 16; ++n)
#pragma unroll
        for (int r = 0; r < 4; ++r)
          po[mi][n][r] += posh[(gw * 32 + mi * 16 + g * 4 + r) * 256 + n * 16 + lr];
#pragma unroll
    for (int mi = 0; mi < 2; ++mi)
#pragma unroll
      for (int r = 0; r < 4; ++r) lsp[mi][r] += lsh[(gw * 64 + lane) * 8 + mi * 4 + r];
#pragma unroll
    for (int off = 1; off < 16; off <<= 1)
#pragma unroll
      for (int mi = 0; mi < 2; ++mi)
#pragma unroll
        for (int r = 0; r < 4; ++r) lsp[mi][r] += __shfl_xor(lsp[mi][r], off, 64);
#pragma unroll
    for (int mi = 0; mi < 2; ++mi)
#pragma unroll
      for (int r = 0; r < 4; ++r) {
        float inv = 1.0f / lsp[mi][r];
        size_t row = (size_t)i0 + gw * 32 + mi * 16 + g * 4 + r;
        unsigned short* op = att + ((size_t)b * SS + row) * 1024 + h * 256 + lr;
#pragma unroll
        for (int n = 0; n < 16; ++n) op[n * 16] = f2b(po[mi][n][r] * inv);
      }
  }
}

extern "C" void kernel_launch(void* const* d_in, const int* in_sizes, int n_in,
                              void* d_out, int out_size, void* d_ws, size_t ws_size,
                              hipStream_t stream) {
  const float* x    = (const float*)d_in[0];
  // d_in[1] = mask (computed analytically)
  const float* cosp = (const float*)d_in[2];
  const float* sinp = (const float*)d_in[3];
  const float* Wq   = (const float*)d_in[4];
  const float* Wk   = (const float*)d_in[5];
  const float* Wv   = (const float*)d_in[6];
  const float* Wo   = (const float*)d_in[7];
  const float* qsc  = (const float*)d_in[8];
  const float* ksc  = (const float*)d_in[9];
  float* out = (float*)d_out;
  char* ws = (char*)d_ws;

  unsigned short* xb   = (unsigned short*)(ws);               // 8192x640 bf16
  unsigned short* wqkv = (unsigned short*)(ws + 10485760);    // 1536x640 bf16 (W^T)
  unsigned short* wo   = (unsigned short*)(ws + 12451840);    // 640x1024 bf16 (Wo^T)
  unsigned short* qkv  = (unsigned short*)(ws + 13762560);    // 8192x1536 bf16
  unsigned short* qb   = (unsigned short*)(ws + 38928384);    // (B,H,S,D) bf16
  unsigned short* kbuf = (unsigned short*)(ws + 55705600);    // (B,S,D) bf16
  unsigned short* vt   = (unsigned short*)(ws + 59899904);    // (B,D,S) bf16
  unsigned short* attb = (unsigned short*)(ws + 64094208);    // (B,S,H*D) bf16

  k_cast_bf16<<<5120, 256, 0, stream>>>(x, xb, 1310720);
  k_transpose_bf16<float><<<dim3(20, 32), 256, 0, stream>>>(Wq, wqkv, 1024, 640);
  k_transpose_bf16<float><<<dim3(20, 8), 256, 0, stream>>>(Wk, wqkv + 1024 * 640, 256, 640);
  k_transpose_bf16<float><<<dim3(20, 8), 256, 0, stream>>>(Wv, wqkv + 1280 * 640, 256, 640);
  k_transpose_bf16<float><<<dim3(32, 20), 256, 0, stream>>>(Wo, wo, 640, 1024);
  k_gemm<true, 128><<<768, 256, 0, stream>>>(xb, wqkv, qkv, 8192, 1536, 640, 12);
  k_normrope<<<8192, 320, 0, stream>>>(qkv, cosp, sinp, qsc, ksc, qb, kbuf);
  k_transpose_bf16<unsigned short><<<dim3(128, 8), 256, 0, stream>>>(qkv + 1280, vt, 1536, 4096);
  k_transpose_bf16<unsigned short><<<dim3(128, 8), 256, 0, stream>>>(
      qkv + (size_t)4096 * 1536 + 1280, vt + (size_t)256 * 4096, 1536, 4096);
  k_attn<<<256, 512, 0, stream>>>(qb, kbuf, vt, attb);
  k_gemm<false, 64><<<640, 256, 0, stream>>>(attb, wo, out, 8192, 640, 1024, 10);
}

// Round 6
// 121.871 us; speedup vs baseline: 1.2609x; 1.2609x over previous
//
#include <hip/hip_runtime.h>
#include <hip/hip_bf16.h>
#include <stdint.h>

#define BB 2
#define SS 4096
#define EE 640
#define HH 4
#define DD 256
#define WIN 512

typedef __attribute__((ext_vector_type(8))) short bv8;    // 8 bf16 (4 VGPR)
typedef __attribute__((ext_vector_type(4))) float fv4;
typedef __attribute__((ext_vector_type(16))) float fv16;  // 32x32 accumulator

__device__ __forceinline__ unsigned short f2b(float f) {
  union { float f; unsigned u; } a; a.f = f;
  unsigned r = a.u + 0x7fffu + ((a.u >> 16) & 1u);   // RNE
  return (unsigned short)(r >> 16);
}
__device__ __forceinline__ float b2f(unsigned short s) {
  union { unsigned u; float f; } a; a.u = ((unsigned)s) << 16;
  return a.f;
}
__device__ __forceinline__ unsigned pk2(float lo, float hi_) {
  return (unsigned)f2b(lo) | ((unsigned)f2b(hi_) << 16);
}

typedef const __attribute__((address_space(1))) unsigned int* as1u;
typedef __attribute__((address_space(3))) unsigned int* as3u;
__device__ __forceinline__ void gld16(const unsigned short* g, unsigned short* l) {
  // async global->LDS, 16B/lane; LDS dst = wave-uniform base + lane*16
  __builtin_amdgcn_global_load_lds((as1u)(const void*)g, (as3u)(void*)l, 16, 0, 0);
}

// ---------------- f32 -> bf16 cast (x) ----------------
__global__ __launch_bounds__(256) void k_cast_bf16(const float* __restrict__ src,
                                                   unsigned short* __restrict__ dst, int n4) {
  int i = blockIdx.x * 256 + threadIdx.x;
  if (i >= n4) return;
  fv4 v = ((const fv4*)src)[i];
  ushort4 o; o.x = f2b(v.x); o.y = f2b(v.y); o.z = f2b(v.z); o.w = f2b(v.w);
  ((ushort4*)dst)[i] = o;
}

// ---------------- tiled transpose + cast to bf16 ----------------
template <typename T>
__global__ __launch_bounds__(256) void k_transpose_bf16(const T* __restrict__ src,
    unsigned short* __restrict__ dst, int sstride, int dstride) {
  __shared__ float tile[32][33];
  int r0 = blockIdx.x * 32, c0 = blockIdx.y * 32;
  int t = threadIdx.x;
  int rr = t >> 3, cc = (t & 7) * 4;
  const T* p = src + (size_t)(r0 + rr) * sstride + c0 + cc;
  float v[4];
  if constexpr (sizeof(T) == 4) {
    fv4 x = *(const fv4*)p;
    v[0] = x.x; v[1] = x.y; v[2] = x.z; v[3] = x.w;
  } else {
    ushort4 x = *(const ushort4*)p;
    v[0] = b2f(x.x); v[1] = b2f(x.y); v[2] = b2f(x.z); v[3] = b2f(x.w);
  }
#pragma unroll
  for (int i = 0; i < 4; ++i) tile[cc + i][rr] = v[i];
  __syncthreads();
  ushort4 o;
  o.x = f2b(tile[rr][cc + 0]); o.y = f2b(tile[rr][cc + 1]);
  o.z = f2b(tile[rr][cc + 2]); o.w = f2b(tile[rr][cc + 3]);
  *(ushort4*)(dst + (size_t)(c0 + rr) * dstride + r0 + cc) = o;
}

// ---------------- bf16 GEMM (m97 structure): C(MxN) = A(MxK) * Bt(NxK)^T ----
template <bool OUT_BF16, int BN>
__global__ __launch_bounds__(256) void k_gemm(const unsigned short* __restrict__ A,
    const unsigned short* __restrict__ Bt, void* __restrict__ Cp,
    int M, int N, int K, int nt_n) {
  __shared__ unsigned short la[128 * 32];
  __shared__ unsigned short lb[BN * 32];
  const int bid = blockIdx.x;
  const int gidx = (bid & 7) * (gridDim.x >> 3) + (bid >> 3);
  const int m0 = (gidx / nt_n) * 128, n0 = (gidx % nt_n) * BN;
  const int tid = threadIdx.x, lane = tid & 63, wave = tid >> 6;
  const int g = lane >> 4, lr = lane & 15;
  constexpr int MI = (BN == 128) ? 4 : 2;
  const int wm = (BN == 128) ? (wave >> 1) * 64 : wave * 32;
  const int wn = (BN == 128) ? (wave & 1) * 64 : 0;
  fv4 acc[MI][4] = {};
  const int srow = wave * 32 + (lane >> 2);
  const int sch = (lane & 3) * 8;
  const unsigned short* ga0 = A + (size_t)(m0 + srow) * K + sch;
  unsigned short* lad = la + wave * 1024;
  const int srowb = (BN == 128) ? srow : (wave * 16 + (lane >> 2));
  const unsigned short* gb0 = Bt + (size_t)(n0 + srowb) * K + sch;
  unsigned short* lbd = lb + ((BN == 128) ? wave * 1024 : wave * 512);
  for (int k0 = 0; k0 < K; k0 += 32) {
    __syncthreads();
    gld16(ga0 + k0, lad);
    gld16(ga0 + (size_t)16 * K + k0, lad + 512);
    gld16(gb0 + k0, lbd);
    if constexpr (BN == 128) gld16(gb0 + (size_t)16 * K + k0, lbd + 512);
    __syncthreads();
    bv8 af[MI], bf[4];
#pragma unroll
    for (int mi = 0; mi < MI; ++mi) af[mi] = *(const bv8*)(la + (wm + mi * 16 + lr) * 32 + g * 8);
#pragma unroll
    for (int ni = 0; ni < 4; ++ni) bf[ni] = *(const bv8*)(lb + (wn + ni * 16 + lr) * 32 + g * 8);
    __builtin_amdgcn_s_setprio(1);
#pragma unroll
    for (int mi = 0; mi < MI; ++mi)
#pragma unroll
      for (int ni = 0; ni < 4; ++ni)
        acc[mi][ni] = __builtin_amdgcn_mfma_f32_16x16x32_bf16(af[mi], bf[ni], acc[mi][ni], 0, 0, 0);
    __builtin_amdgcn_s_setprio(0);
  }
#pragma unroll
  for (int mi = 0; mi < MI; ++mi) {
#pragma unroll
    for (int r = 0; r < 4; ++r) {
      size_t row = (size_t)(m0 + wm + mi * 16 + g * 4 + r);
#pragma unroll
      for (int ni = 0; ni < 4; ++ni) {
        int col = n0 + wn + ni * 16 + lr;
        float val = acc[mi][ni][r];
        if constexpr (OUT_BF16)
          ((unsigned short*)Cp)[row * N + col] = f2b(val);
        else
          ((float*)Cp)[row * N + col] = val;
      }
    }
  }
}

// ---------------- rmsnorm + rope (+ SCALING folded into q), bf16 out --------
__global__ __launch_bounds__(320) void k_normrope(const unsigned short* __restrict__ qkv,
    const float* __restrict__ cosp, const float* __restrict__ sinp,
    const float* __restrict__ qsc, const float* __restrict__ ksc,
    unsigned short* __restrict__ qo, unsigned short* __restrict__ ko) {
  int m = blockIdx.x;
  int b = m >> 12, s = m & 4095;
  int wave = threadIdx.x >> 6, lane = threadIdx.x & 63;
  bool isq = wave < 4;
  const unsigned short* src = qkv + (size_t)m * 1536 + (isq ? wave * 256 : 1024);
  const float* scp = isq ? qsc : ksc;
  int d0 = lane * 4;
  ushort4 raw = *(const ushort4*)(src + d0);
  float x0 = b2f(raw.x), x1 = b2f(raw.y), x2 = b2f(raw.z), x3 = b2f(raw.w);
  float ss = x0 * x0 + x1 * x1 + x2 * x2 + x3 * x3;
#pragma unroll
  for (int off = 1; off < 64; off <<= 1) ss += __shfl_xor(ss, off, 64);
  float rs = rsqrtf(ss * (1.0f / 256.0f) + 1e-6f);
  fv4 sc = *(const fv4*)(scp + d0);
  float n0 = x0 * rs * (1.0f + sc.x);
  float n1 = x1 * rs * (1.0f + sc.y);
  float n2 = x2 * rs * (1.0f + sc.z);
  float n3 = x3 * rs * (1.0f + sc.w);
  float p0 = __shfl_xor(n0, 32, 64);
  float p1 = __shfl_xor(n1, 32, 64);
  float p2 = __shfl_xor(n2, 32, 64);
  float p3 = __shfl_xor(n3, 32, 64);
  float sgn = (lane < 32) ? -1.0f : 1.0f;
  fv4 c4 = *(const fv4*)(cosp + (size_t)s * 256 + d0);
  fv4 s4 = *(const fv4*)(sinp + (size_t)s * 256 + d0);
  float mult = isq ? 0.0625f : 1.0f;
  float o0 = (n0 * c4.x + sgn * p0 * s4.x) * mult;
  float o1 = (n1 * c4.y + sgn * p1 * s4.y) * mult;
  float o2 = (n2 * c4.z + sgn * p2 * s4.z) * mult;
  float o3 = (n3 * c4.w + sgn * p3 * s4.w) * mult;
  ushort4 o; o.x = f2b(o0); o.y = f2b(o1); o.z = f2b(o2); o.w = f2b(o3);
  unsigned short* dst = isq
      ? qo + ((size_t)(b * HH + wave) * SS + s) * 256 + d0
      : ko + ((size_t)b * SS + s) * 256 + d0;
  *(ushort4*)dst = o;
}

// ---------------- flash attention, sliding window 512 ----------------------
// MQA-shared flash attention: block = 512 thr = 8 waves = 4 heads x 2 key-
// halves over a 32-q-row slab. K/V staged ONCE per block serve all 4 heads.
// 32x32x16 MFMA with SWAPPED operands: S^T = mfma(K, Q) (q = lane&31), so P
// stays in registers: 8 pack + 8 shfl_xor(32) convert S^T-layout to the PV
// B-fragment layout. PV: O^T = mfma(V^T, P^T); no P LDS roundtrip.
// Fixed-max softmax (|score|<=16: RMSNorm norms = 16, RoPE norm-preserving,
// SCALING=1/16) -> key-half partials are linear; combined once at the end.
// K+V double-buffered (128 KB) via global_load_lds, both-sides XOR swizzle,
// 1 barrier/tile, full-tile prefetch.
__global__ __launch_bounds__(512, 2) void k_attn(const unsigned short* __restrict__ q,
    const unsigned short* __restrict__ kg, const unsigned short* __restrict__ vtg,
    unsigned short* __restrict__ att) {
  __shared__ __align__(16) char ldsbuf[133120];   // K/V tiles; reused as combine buf
  __shared__ float lsb[4][32];
  unsigned short* kt = (unsigned short*)ldsbuf;           // [2][64*256]
  unsigned short* vl = (unsigned short*)ldsbuf + 32768;   // [2][256*64]
  const int bid = blockIdx.x;
  const int gidx = (bid & 7) * 32 + (bid >> 3);   // XCD-chunked (256 blocks)
  const int b = gidx >> 7;
  const int i0 = (gidx & 127) * 32;
  const int tid = threadIdx.x, wave = tid >> 6, lane = tid & 63;
  const int h = wave >> 1, ks = wave & 1;
  const int hi = lane >> 5, l31 = lane & 31;
  // Q B-fragments: B[k][q], col=q=lane&31, k = m*16 + hi*8 + e
  bv8 qf[16];
  {
    const unsigned short* qp = q + ((size_t)(b * HH + h) * SS + i0 + l31) * 256;
#pragma unroll
    for (int m = 0; m < 16; ++m) qf[m] = *(const bv8*)(qp + m * 16 + hi * 8);
  }
  fv16 po[8] = {};
  float lsp = 0.f;
  const int t0 = (i0 >= WIN) ? ((i0 - WIN + 1) >> 6) : 0;
  const int t1 = i0 >> 6;
  const unsigned short* kb = kg + (size_t)b * SS * 256;
  const unsigned short* vb = vtg + (size_t)b * 256 * SS;
  // K stage: 64 rows x 512B = 2048 16B-slots; LDS slot s of row r holds
  // global chunk s^(r&7). 4 calls x 512 threads.
  auto stageK = [&](int t, int pp) {
    const unsigned short* kbase = kb + (size_t)t * 64 * 256;
    unsigned short* dst = kt + pp * 16384;
#pragma unroll
    for (int c = 0; c < 4; ++c) {
      int slot = c * 512 + tid;
      int row = slot >> 5, s = slot & 31;
      gld16(kbase + (size_t)row * 256 + ((s ^ (row & 7)) * 8),
            dst + (c * 512 + wave * 64) * 8);
    }
  };
  // V stage: 256 d-rows x 128B = 2048 slots; slot s of row d holds chunk s^(d&7)
  auto stageV = [&](int t, int pp) {
    const unsigned short* vbase = vb + (size_t)t * 64;
    unsigned short* dst = vl + pp * 16384;
#pragma unroll
    for (int c = 0; c < 4; ++c) {
      int slot = c * 512 + tid;
      int d_ = slot >> 3, s = slot & 7;
      gld16(vbase + (size_t)d_ * SS + ((s ^ (d_ & 7)) * 8),
            dst + (c * 512 + wave * 64) * 8);
    }
  };
  stageK(t0, 0); stageV(t0, 0);
  int p = 0;
  const int krow = ks * 32 + l31;        // K-frag row (key within tile)
  const int krx = krow & 7;
  const int vrx = l31 & 7;               // V-frag row&7 (d_&7 == l31&7)
  for (int t = t0; t <= t1; ++t) {
    __syncthreads();   // drains staging of buf p; prior iter's reads of p^1 done
    if (t < t1) { stageK(t + 1, p ^ 1); stageV(t + 1, p ^ 1); }
    // ---- QK^T (swapped): S^T[key][q] ----
    fv16 sa = {};
    const unsigned short* ktp = kt + p * 16384 + krow * 256;
    __builtin_amdgcn_s_setprio(1);
#pragma unroll
    for (int m = 0; m < 16; ++m) {
      bv8 kf = *(const bv8*)(ktp + (((m * 2 + hi) ^ krx) * 8));
      sa = __builtin_amdgcn_mfma_f32_32x32x16_bf16(kf, qf[m], sa, 0, 0, 0);
    }
    __builtin_amdgcn_s_setprio(0);
    // ---- mask + exp (fixed max) + pack into PV B-frag layout ----
    const int jb = t * 64;
    const int kb0 = jb + ks * 32;
    const bool nm = (kb0 + 31 > i0) || (i0 + 31 - kb0 >= WIN);
    if (nm) {
      const int qa = i0 + l31;
#pragma unroll
      for (int r = 0; r < 16; ++r) {
        int j = kb0 + (r & 3) + 8 * (r >> 2) + 4 * hi;
        if (j > qa || qa - j >= WIN) sa[r] = -1e30f;
      }
    }
    unsigned a[8];
#pragma unroll
    for (int i = 0; i < 8; ++i) {
      float e0 = __expf(sa[2 * i] - 16.5f);
      float e1 = __expf(sa[2 * i + 1] - 16.5f);
      lsp += e0 + e1;
      a[i] = pk2(e0, e1);
    }
    // exchange hi-halves: lane l <-> l^32 (P^T B-frag: k = m2*16 + hi*8 + e)
    unsigned w[8];
#pragma unroll
    for (int m2 = 0; m2 < 2; ++m2) {
      unsigned a0 = a[m2 * 4 + 0], a1 = a[m2 * 4 + 1];
      unsigned a2 = a[m2 * 4 + 2], a3 = a[m2 * 4 + 3];
      unsigned s0 = (unsigned)__shfl_xor((int)a0, 32, 64);
      unsigned s1 = (unsigned)__shfl_xor((int)a1, 32, 64);
      unsigned s2 = (unsigned)__shfl_xor((int)a2, 32, 64);
      unsigned s3 = (unsigned)__shfl_xor((int)a3, 32, 64);
      w[m2 * 4 + 0] = hi ? s2 : a0;
      w[m2 * 4 + 1] = hi ? s3 : a1;
      w[m2 * 4 + 2] = hi ? a2 : s0;
      w[m2 * 4 + 3] = hi ? a3 : s1;
    }
    // ---- PV: O^T[d][q] += V^T[d][k] * P^T[k][q] ----
    const unsigned short* vlp = vl + p * 16384;
    __builtin_amdgcn_s_setprio(1);
#pragma unroll
    for (int m2 = 0; m2 < 2; ++m2) {
      union { unsigned u[4]; bv8 v; } pf;
      pf.u[0] = w[m2 * 4 + 0]; pf.u[1] = w[m2 * 4 + 1];
      pf.u[2] = w[m2 * 4 + 2]; pf.u[3] = w[m2 * 4 + 3];
      const int slot = (ks * 4 + m2 * 2 + hi) ^ vrx;
#pragma unroll
      for (int ds_ = 0; ds_ < 8; ++ds_) {
        bv8 vf = *(const bv8*)(vlp + (ds_ * 32 + l31) * 64 + slot * 8);
        po[ds_] = __builtin_amdgcn_mfma_f32_32x32x16_bf16(vf, pf.v, po[ds_], 0, 0, 0);
      }
    }
    __builtin_amdgcn_s_setprio(0);
    p ^= 1;
  }
  // ---- combine the two key-halves (fixed-max partials are linear) ----
  float lsfull = lsp + __shfl_xor(lsp, 32, 64);
  __syncthreads();
  float* cb = (float*)ldsbuf;            // rows 128 (h*32+q) x stride 260 f32
  if (ks == 1) {
#pragma unroll
    for (int ds_ = 0; ds_ < 8; ++ds_)
#pragma unroll
      for (int j = 0; j < 4; ++j) {
        int d0 = ds_ * 32 + 8 * j + 4 * hi;
        fv4 v4; v4[0] = po[ds_][4 * j]; v4[1] = po[ds_][4 * j + 1];
        v4[2] = po[ds_][4 * j + 2]; v4[3] = po[ds_][4 * j + 3];
        *(fv4*)(cb + (h * 32 + l31) * 260 + d0) = v4;
      }
    if (lane < 32) lsb[h][lane] = lsfull;
  }
  __syncthreads();
  if (ks == 0) {
    float total = lsfull + lsb[h][l31];
    float inv = 1.0f / total;
    unsigned short* op = att + ((size_t)b * SS + i0 + l31) * 1024 + h * 256;
#pragma unroll
    for (int ds_ = 0; ds_ < 8; ++ds_)
#pragma unroll
      for (int j = 0; j < 4; ++j) {
        int d0 = ds_ * 32 + 8 * j + 4 * hi;
        fv4 v4 = *(const fv4*)(cb + (h * 32 + l31) * 260 + d0);
        ushort4 o;
        o.x = f2b((po[ds_][4 * j] + v4[0]) * inv);
        o.y = f2b((po[ds_][4 * j + 1] + v4[1]) * inv);
        o.z = f2b((po[ds_][4 * j + 2] + v4[2]) * inv);
        o.w = f2b((po[ds_][4 * j + 3] + v4[3]) * inv);
        *(ushort4*)(op + d0) = o;
      }
  }
}

extern "C" void kernel_launch(void* const* d_in, const int* in_sizes, int n_in,
                              void* d_out, int out_size, void* d_ws, size_t ws_size,
                              hipStream_t stream) {
  const float* x    = (const float*)d_in[0];
  // d_in[1] = mask (computed analytically)
  const float* cosp = (const float*)d_in[2];
  const float* sinp = (const float*)d_in[3];
  const float* Wq   = (const float*)d_in[4];
  const float* Wk   = (const float*)d_in[5];
  const float* Wv   = (const float*)d_in[6];
  const float* Wo   = (const float*)d_in[7];
  const float* qsc  = (const float*)d_in[8];
  const float* ksc  = (const float*)d_in[9];
  float* out = (float*)d_out;
  char* ws = (char*)d_ws;

  unsigned short* xb   = (unsigned short*)(ws);               // 8192x640 bf16
  unsigned short* wqkv = (unsigned short*)(ws + 10485760);    // 1536x640 bf16 (W^T)
  unsigned short* wo   = (unsigned short*)(ws + 12451840);    // 640x1024 bf16 (Wo^T)
  unsigned short* qkv  = (unsigned short*)(ws + 13762560);    // 8192x1536 bf16
  unsigned short* qb   = (unsigned short*)(ws + 38928384);    // (B,H,S,D) bf16
  unsigned short* kbuf = (unsigned short*)(ws + 55705600);    // (B,S,D) bf16
  unsigned short* vt   = (unsigned short*)(ws + 59899904);    // (B,D,S) bf16
  unsigned short* attb = (unsigned short*)(ws + 64094208);    // (B,S,H*D) bf16

  k_cast_bf16<<<5120, 256, 0, stream>>>(x, xb, 1310720);
  k_transpose_bf16<float><<<dim3(20, 32), 256, 0, stream>>>(Wq, wqkv, 1024, 640);
  k_transpose_bf16<float><<<dim3(20, 8), 256, 0, stream>>>(Wk, wqkv + 1024 * 640, 256, 640);
  k_transpose_bf16<float><<<dim3(20, 8), 256, 0, stream>>>(Wv, wqkv + 1280 * 640, 256, 640);
  k_transpose_bf16<float><<<dim3(32, 20), 256, 0, stream>>>(Wo, wo, 640, 1024);
  k_gemm<true, 128><<<768, 256, 0, stream>>>(xb, wqkv, qkv, 8192, 1536, 640, 12);
  k_normrope<<<8192, 320, 0, stream>>>(qkv, cosp, sinp, qsc, ksc, qb, kbuf);
  k_transpose_bf16<unsigned short><<<dim3(128, 8), 256, 0, stream>>>(qkv + 1280, vt, 1536, 4096);
  k_transpose_bf16<unsigned short><<<dim3(128, 8), 256, 0, stream>>>(
      qkv + (size_t)4096 * 1536 + 1280, vt + (size_t)256 * 4096, 1536, 4096);
  k_attn<<<256, 512, 0, stream>>>(qb, kbuf, vt, attb);
  k_gemm<false, 64><<<640, 256, 0, stream>>>(attb, wo, out, 8192, 640, 1024, 10);
}